// Round 6
// baseline (262.065 us; speedup 1.0000x reference)
//
#include <hip/hip_runtime.h>
#include <hip/hip_bf16.h>
#include <math.h>

#define HID 2048
#define NH 16
#define NKV 8
#define HD 128
#define SEQ 2048
#define EPS 1e-6f
#define THETA 10000.0f
#define SCALE 0.08838834764831845f  // 128^-0.5
#define DTHR 90.50966799187809f     // 8 / SCALE: defer-max threshold in raw-score units

typedef __attribute__((ext_vector_type(8))) short bf8_t;   // 8 bf16 (4 VGPRs)
typedef __attribute__((ext_vector_type(4))) short bf4_t;   // 4 bf16 (2 VGPRs)
typedef __attribute__((ext_vector_type(4))) float f4_t;    // 4 fp32

__device__ __forceinline__ short f2bf(float f) {
    union { __hip_bfloat16 h; short s; } u;
    u.h = __float2bfloat16(f);
    return u.s;
}
__device__ __forceinline__ float bf2f(short s) {
    union { short s; __hip_bfloat16 h; } u;
    u.s = s;
    return __bfloat162float(u.h);
}
__device__ __forceinline__ bf8_t pack8(const float4& a, const float4& b) {
    bf8_t r;
    r[0] = f2bf(a.x); r[1] = f2bf(a.y); r[2] = f2bf(a.z); r[3] = f2bf(a.w);
    r[4] = f2bf(b.x); r[5] = f2bf(b.y); r[6] = f2bf(b.z); r[7] = f2bf(b.w);
    return r;
}
// async global->LDS DMA, 16 B per lane; lds dest = wave-uniform base + lane*16
__device__ __forceinline__ void gload16(const short* g, short* l) {
    __builtin_amdgcn_global_load_lds(
        (const __attribute__((address_space(1))) unsigned int*)g,
        (__attribute__((address_space(3))) unsigned int*)l, 16, 0, 0);
}

__device__ __forceinline__ float wave_reduce_sum(float v) {
#pragma unroll
    for (int off = 32; off > 0; off >>= 1) v += __shfl_xor(v, off);
    return v;
}

// ---------------- 1. fused prep: f2bf(w_qkv) | f2bf(w_o) | hidden RMSNorm ------
__global__ __launch_bounds__(256) void prep_kernel(
    const float* __restrict__ w_qkv, short* __restrict__ wqb,
    const float* __restrict__ w_o, short* __restrict__ wob,
    const float* __restrict__ x, const float* __restrict__ w,
    short* __restrict__ out) {
    int bid = blockIdx.x;
    int tid = threadIdx.x;
    if (bid < 4096) {
        int i = bid * 256 + tid;
        float4 a = *(const float4*)(w_qkv + (size_t)i * 8);
        float4 b = *(const float4*)(w_qkv + (size_t)i * 8 + 4);
        *(bf8_t*)(wqb + (size_t)i * 8) = pack8(a, b);
        return;
    }
    if (bid < 6144) {
        int i = (bid - 4096) * 256 + tid;
        float4 a = *(const float4*)(w_o + (size_t)i * 8);
        float4 b = *(const float4*)(w_o + (size_t)i * 8 + 4);
        *(bf8_t*)(wob + (size_t)i * 8) = pack8(a, b);
        return;
    }
    int row = bid - 6144;
    const float* xr = x + (size_t)row * HID;
    float4 a = *(const float4*)(xr + tid * 8);
    float4 b = *(const float4*)(xr + tid * 8 + 4);
    float ss = a.x * a.x + a.y * a.y + a.z * a.z + a.w * a.w +
               b.x * b.x + b.y * b.y + b.z * b.z + b.w * b.w;
    ss = wave_reduce_sum(ss);
    __shared__ float part[4];
    __shared__ float s_scale;
    if ((tid & 63) == 0) part[tid >> 6] = ss;
    __syncthreads();
    if (tid == 0) {
        float t = part[0] + part[1] + part[2] + part[3];
        s_scale = rsqrtf(t / (float)HID + EPS);
    }
    __syncthreads();
    float sc = s_scale;
    float4 wa = *(const float4*)(w + tid * 8);
    float4 wb = *(const float4*)(w + tid * 8 + 4);
    float4 oa = make_float4(a.x * sc * wa.x, a.y * sc * wa.y,
                            a.z * sc * wa.z, a.w * sc * wa.w);
    float4 ob = make_float4(b.x * sc * wb.x, b.y * sc * wb.y,
                            b.z * sc * wb.z, b.w * sc * wb.w);
    *(bf8_t*)(out + (size_t)row * HID + tid * 8) = pack8(oa, ob);
}

// ---------------- 2. gemm1 v7: 256x256 tile, 8 waves, counted-vmcnt pipeline ----
// C = A @ B^T (A = hn bf16 [2048][2048], B = w_qkv bf16 [4096][2048]).
// Split-K=2 via blockIdx.z -> bf16 partials pA/pB [2048][4096] (mid fuses add).
// Schedule: BK=32, triple-buffered LDS (3 x 32 KB), prefetch distance 2,
// raw s_barrier + hand-counted s_waitcnt vmcnt(8/4/0) -- NEVER vmcnt(0) in
// steady state (T4: counted-vs-drain = +38-73%, m218). __syncthreads is not
// used anywhere: it would drain the prefetch queue (r4 regression mechanism).
// LDS swizzle: 4-chunk row rotation by (row>>1) -> 2-way bank alias = free.
#define G1_N 4096
#define G1_T 32   // K-tiles per block: 1024 / 32
__global__ __launch_bounds__(512) void gemm1_v7_kernel(
    const short* __restrict__ A, const short* __restrict__ B,
    short* __restrict__ pA, short* __restrict__ pB) {
    __shared__ short SA[3][256][32];
    __shared__ short SB[3][256][32];
    int tid = threadIdx.x;
    int w = tid >> 6, lane = tid & 63;
    int n16 = lane & 15, qd = lane >> 4;
    int m0 = blockIdx.y * 256, n0 = blockIdx.x * 256;
    int z = blockIdx.z;
    int kbeg = z ? (HID / 2) : 0;
    short* Pp = z ? pB : pA;
    int wm = (w >> 2) * 128, wn = (w & 3) * 64;

    // staging: per wave 2 A-gloads + 2 B-gloads per K-tile (16 rows each).
    // lane l writes LDS row (base + l>>2), slot l&3; global chunk pre-rotated.
    size_t aBase[2], bBase[2];
#pragma unroll
    for (int it = 0; it < 2; ++it) {
        int rl = w * 32 + it * 16 + (lane >> 2);      // local row 0..255
        int c = ((lane & 3) - (rl >> 1)) & 3;         // inverse-rotated chunk
        aBase[it] = (size_t)(m0 + rl) * HID + kbeg + c * 8;
        bBase[it] = (size_t)(n0 + rl) * HID + kbeg + c * 8;
    }

    f4_t acc[8][4];
#pragma unroll
    for (int m = 0; m < 8; ++m)
#pragma unroll
        for (int nn = 0; nn < 4; ++nn) acc[m][nn] = (f4_t){0.f, 0.f, 0.f, 0.f};

    auto stage = [&](int buf, int t) {
        int ko = t * 32;
#pragma unroll
        for (int it = 0; it < 2; ++it)
            gload16(A + aBase[it] + ko, &SA[buf][w * 32 + it * 16][0]);
#pragma unroll
        for (int it = 0; it < 2; ++it)
            gload16(B + bBase[it] + ko, &SB[buf][w * 32 + it * 16][0]);
    };

    stage(0, 0);
    stage(1, 1);
    int cur = 0;
    for (int t = 0; t < G1_T; ++t) {
        if (t + 2 < G1_T) stage((cur + 2) % 3, t + 2);   // issue-early, depth 2
        // wait only for tile t's 4 loads/wave (issued 2 iters ago); newer stay in flight
        if (t < G1_T - 2)       asm volatile("s_waitcnt vmcnt(8)" ::: "memory");
        else if (t == G1_T - 2) asm volatile("s_waitcnt vmcnt(4)" ::: "memory");
        else                    asm volatile("s_waitcnt vmcnt(0)" ::: "memory");
        __builtin_amdgcn_s_barrier();
        asm volatile("" ::: "memory");

        bf8_t af[8], bfv[4];
#pragma unroll
        for (int m = 0; m < 8; ++m) {
            int row = wm + m * 16 + n16;
            af[m] = *(const bf8_t*)&SA[cur][row][((qd + (row >> 1)) & 3) * 8];
        }
#pragma unroll
        for (int nn = 0; nn < 4; ++nn) {
            int row = wn + nn * 16 + n16;
            bfv[nn] = *(const bf8_t*)&SB[cur][row][((qd + (row >> 1)) & 3) * 8];
        }
        __builtin_amdgcn_s_setprio(1);
#pragma unroll
        for (int m = 0; m < 8; ++m)
#pragma unroll
            for (int nn = 0; nn < 4; ++nn)
                acc[m][nn] = __builtin_amdgcn_mfma_f32_16x16x32_bf16(
                    af[m], bfv[nn], acc[m][nn], 0, 0, 0);
        __builtin_amdgcn_s_setprio(0);
        asm volatile("" ::: "memory");
        __builtin_amdgcn_s_barrier();   // MFMA consumed buf[cur] -> safe to overwrite
        cur = (cur + 1) == 3 ? 0 : (cur + 1);
    }

#pragma unroll
    for (int m = 0; m < 8; ++m)
#pragma unroll
        for (int nn = 0; nn < 4; ++nn)
#pragma unroll
            for (int r = 0; r < 4; ++r) {
                int gm = m0 + wm + m * 16 + qd * 4 + r;
                int gn = n0 + wn + nn * 16 + n16;
                Pp[(size_t)gm * G1_N + gn] = f2bf(acc[m][nn][r]);
            }
}

// ---------------- 5. gemm2: 128^2 bf16 MFMA GEMM, split-K=2 f32 partials ------
__global__ __launch_bounds__(256) void gemm_mfma_kernel(
    const short* __restrict__ A, const short* __restrict__ B,
    float* __restrict__ C0, float* __restrict__ C1, int M, int N, int K) {
    __shared__ short As[128][64];
    __shared__ short Bs[128][64];
    int tid = threadIdx.x;
    int wv = tid >> 6, lane = tid & 63;
    int n16 = lane & 15, qd = lane >> 4;
    int m0 = blockIdx.y * 128, n0 = blockIdx.x * 128;
    int wm = (wv >> 1) * 64, wn = (wv & 1) * 64;
    int sr8 = lane >> 3, slot = lane & 7;

    int z = blockIdx.z;
    int kbeg = z ? (K >> 1) : 0;
    int kend = z ? K : (K >> 1);
    float* Cf = z ? C1 : C0;

    size_t ainv[4], binv[4];
#pragma unroll
    for (int it = 0; it < 4; ++it) {
        int row = wv * 32 + it * 8 + sr8;
        int chunk = (slot - row) & 7;
        ainv[it] = (size_t)(m0 + row) * K + chunk * 8;
        binv[it] = (size_t)(n0 + row) * K + chunk * 8;
    }

    f4_t acc[4][4];
#pragma unroll
    for (int i = 0; i < 4; ++i)
#pragma unroll
        for (int j = 0; j < 4; ++j) acc[i][j] = (f4_t){0.f, 0.f, 0.f, 0.f};

    for (int k0 = kbeg; k0 < kend; k0 += 64) {
        __syncthreads();
#pragma unroll
        for (int it = 0; it < 4; ++it) {
            gload16(A + ainv[it] + k0, &As[wv * 32 + it * 8][0]);
            gload16(B + binv[it] + k0, &Bs[wv * 32 + it * 8][0]);
        }
        __syncthreads();

        bf8_t af[4][2], bf[4][2];
#pragma unroll
        for (int t = 0; t < 4; ++t)
#pragma unroll
            for (int ks = 0; ks < 2; ++ks) {
                int ar = wm + t * 16 + n16;
                af[t][ks] = *(const bf8_t*)&As[ar][(((ks * 4 + qd) + ar) & 7) * 8];
                int br = wn + t * 16 + n16;
                bf[t][ks] = *(const bf8_t*)&Bs[br][(((ks * 4 + qd) + br) & 7) * 8];
            }
#pragma unroll
        for (int ks = 0; ks < 2; ++ks)
#pragma unroll
            for (int mt = 0; mt < 4; ++mt)
#pragma unroll
                for (int nt = 0; nt < 4; ++nt)
                    acc[mt][nt] = __builtin_amdgcn_mfma_f32_16x16x32_bf16(
                        af[mt][ks], bf[nt][ks], acc[mt][nt], 0, 0, 0);
    }

#pragma unroll
    for (int mt = 0; mt < 4; ++mt)
#pragma unroll
        for (int nt = 0; nt < 4; ++nt)
#pragma unroll
            for (int r = 0; r < 4; ++r) {
                int gm = m0 + wm + mt * 16 + qd * 4 + r;
                int gn = n0 + wn + nt * 16 + n16;
                Cf[(size_t)gm * N + gn] = acc[mt][nt][r];
            }
}

// ---------------- 5b. split-K reduce: out = P0 + P1 (HBM-bound) --------
__global__ __launch_bounds__(256) void splitk_reduce_kernel(
    const float* __restrict__ p0, const float* __restrict__ p1,
    float* __restrict__ o) {
    size_t i = ((size_t)blockIdx.x * 256 + threadIdx.x) * 8;
    float4 a0 = *(const float4*)(p0 + i);
    float4 a1 = *(const float4*)(p0 + i + 4);
    float4 b0 = *(const float4*)(p1 + i);
    float4 b1 = *(const float4*)(p1 + i + 4);
    *(float4*)(o + i) =
        make_float4(a0.x + b0.x, a0.y + b0.y, a0.z + b0.z, a0.w + b0.w);
    *(float4*)(o + i + 4) =
        make_float4(a1.x + b1.x, a1.y + b1.y, a1.z + b1.z, a1.w + b1.w);
}

// ---------------- 3. fused mid: gemm1 partial-add + V transpose | q/k RMSNorm+RoPE
__global__ __launch_bounds__(256) void mid_kernel(
    const short* __restrict__ pA, const short* __restrict__ pB,
    short* __restrict__ vt, short* __restrict__ q, short* __restrict__ k,
    const float* __restrict__ qw, const float* __restrict__ kw,
    const int* __restrict__ pos) {
    int bid = blockIdx.x;
    int tid = threadIdx.x;
    if (bid < 512) {  // ---- V transpose, 64x64 tile ----
        __shared__ short t[64][64];
        int s0 = (bid & 31) * 64, d0 = (bid >> 5) * 64;
        int sl = tid >> 3, ch = tid & 7;
#pragma unroll
        for (int it = 0; it < 2; ++it) {
            int s_local = it * 32 + sl;
            size_t off = (size_t)(s0 + s_local) * 4096 + 3072 + d0 + ch * 8;
            bf8_t a = *(const bf8_t*)(pA + off);
            bf8_t b = *(const bf8_t*)(pB + off);
            bf8_t vv;
#pragma unroll
            for (int j = 0; j < 8; ++j) vv[j] = f2bf(bf2f(a[j]) + bf2f(b[j]));
            *(bf8_t*)&t[s_local][((ch + s_local) & 7) * 8] = vv;
        }
        __syncthreads();
#pragma unroll
        for (int it = 0; it < 2; ++it) {
            int d_local = it * 32 + sl;
            int sbase = ch * 8;
            bf8_t o;
#pragma unroll
            for (int j = 0; j < 8; ++j) {
                int s = sbase + j;
                o[j] = t[s][(((d_local >> 3) + s) & 7) * 8 + (d_local & 7)];
            }
            *(bf8_t*)(vt + (size_t)(d0 + d_local) * SEQ + s0 + sbase) = o;
        }
        return;
    }
    // ---- q/k partial-add + RMSNorm + RoPE: two 128-thread units per block ----
    int u = (bid - 512) * 2 + (tid >> 7);
    int ui = tid >> 7, d = tid & 127;
    int s = u / 24, hh = u % 24;
    int col;
    short* optr;
    const float* w;
    if (hh < NH) {
        col = hh * HD + d;
        optr = q + (size_t)s * (NH * HD) + hh * HD;
        w = qw;
    } else {
        col = 2048 + (hh - NH) * HD + d;
        optr = k + (size_t)s * (NKV * HD) + (hh - NH) * HD;
        w = kw;
    }
    size_t poff = (size_t)s * 4096 + col;
    float x = bf2f(pA[poff]) + bf2f(pB[poff]);
    float ss = wave_reduce_sum(x * x);
    __shared__ float part[2][2];
    if ((d & 63) == 0) part[ui][d >> 6] = ss;
    __syncthreads();
    float tot = part[ui][0] + part[ui][1];
    float xn = x * rsqrtf(tot / (float)HD + EPS) * w[d];
    __shared__ float sh[2][HD];
    sh[ui][d] = xn;
    __syncthreads();
    int j = d & 63;
    float inv = __expf((float)j * -0.14391156831f);  // 10000^(-j/64), fast exp
    float fr = (float)pos[s] * inv;
    float sn, cs;
    __sincosf(fr, &sn, &cs);
    float o;
    if (d < 64)
        o = xn * cs - sh[ui][d + 64] * sn;
    else
        o = xn * cs + sh[ui][d - 64] * sn;
    optr[d] = f2bf(o);
}

// ---------------- 4. MFMA flash attention v6: swapped-QK^T, lane-local rows ----
__device__ __forceinline__ void attn_stage(
    short (&kb)[64][128], short (&vb)[128][64],
    const short* __restrict__ kg, const short* __restrict__ vg,
    int t0, const int (&kinv)[4], const int (&vinv)[4], int wv) {
#pragma unroll
    for (int it = 0; it < 4; ++it) {
        gload16(kg + (size_t)t0 * (NKV * HD) + kinv[it], &kb[wv * 16 + it * 4][0]);
        gload16(vg + t0 + vinv[it], &vb[wv * 32 + it * 8][0]);
    }
}

__device__ __forceinline__ void attn_tile(
    const short (&kb)[64][128], const short (&vb)[128][64],
    short (&psh)[4][2][16][64],
    const bf8_t (&qf)[2][4], f4_t (&of)[2][8],
    float (&m_i)[2], float (&l_p)[2],
    int wv, int n, int qd, int koff) {
    f4_t sc[2][4];
#pragma unroll
    for (int g = 0; g < 2; ++g)
#pragma unroll
        for (int kk = 0; kk < 4; ++kk) sc[g][kk] = (f4_t){0.f, 0.f, 0.f, 0.f};
    __builtin_amdgcn_s_setprio(1);
#pragma unroll
    for (int kk = 0; kk < 4; ++kk) {
        int key = kk * 16 + n;
#pragma unroll
        for (int ks = 0; ks < 4; ++ks) {
            bf8_t kf = *(const bf8_t*)&kb[key][(((ks * 4 + qd) + key) & 15) * 8];
            sc[0][kk] = __builtin_amdgcn_mfma_f32_16x16x32_bf16(kf, qf[0][ks], sc[0][kk], 0, 0, 0);
            sc[1][kk] = __builtin_amdgcn_mfma_f32_16x16x32_bf16(kf, qf[1][ks], sc[1][kk], 0, 0, 0);
        }
    }
    __builtin_amdgcn_s_setprio(0);
#pragma unroll
    for (int g = 0; g < 2; ++g) {
        int rows0 = wv * 32 + g * 16;
        int qrow = rows0 + n;
        if (koff + 63 > rows0) {
#pragma unroll
            for (int kk = 0; kk < 4; ++kk)
#pragma unroll
                for (int r = 0; r < 4; ++r)
                    if (koff + kk * 16 + qd * 4 + r > qrow) sc[g][kk][r] = -1e30f;
        }
        float m01 = fmaxf(fmaxf(fmaxf(sc[g][0][0], sc[g][0][1]), fmaxf(sc[g][0][2], sc[g][0][3])),
                          fmaxf(fmaxf(sc[g][1][0], sc[g][1][1]), fmaxf(sc[g][1][2], sc[g][1][3])));
        float m23 = fmaxf(fmaxf(fmaxf(sc[g][2][0], sc[g][2][1]), fmaxf(sc[g][2][2], sc[g][2][3])),
                          fmaxf(fmaxf(sc[g][3][0], sc[g][3][1]), fmaxf(sc[g][3][2], sc[g][3][3])));
        float mx = fmaxf(m01, m23);
        mx = fmaxf(mx, __shfl_xor(mx, 16));
        mx = fmaxf(mx, __shfl_xor(mx, 32));
        if (!__all(mx <= m_i[g] + DTHR)) {
            float mnew = fmaxf(m_i[g], mx);
            float al = __expf((m_i[g] - mnew) * SCALE);
            m_i[g] = mnew;
            l_p[g] *= al;
#pragma unroll
            for (int r = 0; r < 4; ++r) {
                float alr = __shfl(al, qd * 4 + r);
#pragma unroll
                for (int nb = 0; nb < 8; ++nb) of[g][nb][r] *= alr;
            }
        }
        float mcur = m_i[g];
        float lsum = 0.f;
#pragma unroll
        for (int kk = 0; kk < 4; ++kk) {
            bf4_t pk;
#pragma unroll
            for (int r = 0; r < 4; ++r) {
                float p = __expf((sc[g][kk][r] - mcur) * SCALE);
                lsum += p;
                pk[r] = f2bf(p);
            }
            *(bf4_t*)&psh[wv][g][n][(kk * 16 + qd * 4 + n * 8) & 63] = pk;
        }
        l_p[g] += lsum;
    }
    __builtin_amdgcn_wave_barrier();  // psh write->read, same wave (in-order LDS)
    __builtin_amdgcn_s_setprio(1);
#pragma unroll
    for (int ks2 = 0; ks2 < 2; ++ks2) {
        bf8_t pf0 = *(const bf8_t*)&psh[wv][0][n][((ks2 * 32 + qd * 8) + n * 8) & 63];
        bf8_t pf1 = *(const bf8_t*)&psh[wv][1][n][((ks2 * 32 + qd * 8) + n * 8) & 63];
#pragma unroll
        for (int nb = 0; nb < 8; ++nb) {
            int dim = nb * 16 + n;
            bf8_t vf = *(const bf8_t*)&vb[dim][(((ks2 * 4 + qd) + dim) & 7) * 8];
            of[0][nb] = __builtin_amdgcn_mfma_f32_16x16x32_bf16(pf0, vf, of[0][nb], 0, 0, 0);
            of[1][nb] = __builtin_amdgcn_mfma_f32_16x16x32_bf16(pf1, vf, of[1][nb], 0, 0, 0);
        }
    }
    __builtin_amdgcn_s_setprio(0);
}

__global__ __launch_bounds__(256, 2) void attn_chunk_kernel(
    const short* __restrict__ q, const short* __restrict__ k,
    const short* __restrict__ vt, short* __restrict__ opart,
    float* __restrict__ ml) {
    __shared__ short kbufA[64][128], kbufB[64][128];
    __shared__ short vbufA[128][64], vbufB[128][64];
    __shared__ short psh[4][2][16][64];   // total LDS = 80 KB -> 2 blocks/CU

    int tid = threadIdx.x;
    int wv = tid >> 6, lane = tid & 63;
    int n = lane & 15, qd = lane >> 4;

    int i = blockIdx.x;               // 512 blocks
    int hs = i >> 8, p = i & 255;
    int h = p >> 4;
    int qt = hs ? (p & 15) : (15 - (p & 15));
    int c = hs;
    int qbase = qt * 128;
    int tstart = c ? (qt + 1) : 0;
    int tcount = qt + 1;
    int kvh = h >> 1;

    int kinv[4], vinv[4];
#pragma unroll
    for (int it = 0; it < 4; ++it) {
        int key = wv * 16 + it * 4 + (lane >> 4);
        int ck = ((lane & 15) - key) & 15;
        kinv[it] = key * (NKV * HD) + kvh * HD + ck * 8;
        int dim = wv * 32 + it * 8 + (lane >> 3);
        int cv = ((lane & 7) - dim) & 7;
        vinv[it] = (kvh * HD + dim) * SEQ + cv * 8;
    }

    bf8_t qf[2][4];
#pragma unroll
    for (int g = 0; g < 2; ++g) {
        const short* qp =
            q + (size_t)(qbase + wv * 32 + g * 16 + n) * (NH * HD) + h * HD + qd * 8;
#pragma unroll
        for (int ks = 0; ks < 4; ++ks) qf[g][ks] = *(const bf8_t*)(qp + ks * 32);
    }

    f4_t of[2][8];
#pragma unroll
    for (int g = 0; g < 2; ++g)
#pragma unroll
        for (int x = 0; x < 8; ++x) of[g][x] = (f4_t){0.f, 0.f, 0.f, 0.f};
    float m_i[2] = {-1e30f, -1e30f};
    float l_p[2] = {0.f, 0.f};

    attn_stage(kbufA, vbufA, k, vt, tstart * 64, kinv, vinv, wv);
    for (int tt = 0; tt < tcount; tt += 2) {
        __syncthreads();  // drains DMA for tile tt (issued a full tile ago)
        if (tt + 1 < tcount)
            attn_stage(kbufB, vbufB, k, vt, (tstart + tt + 1) * 64, kinv, vinv, wv);
        attn_tile(kbufA, vbufA, psh, qf, of, m_i, l_p, wv, n, qd,
                  (tstart + tt) * 64 - qbase);
        if (tt + 1 < tcount) {
            __syncthreads();
            if (tt + 2 < tcount)
                attn_stage(kbufA, vbufA, k, vt, (tstart + tt + 2) * 64, kinv, vinv, wv);
            attn_tile(kbufB, vbufB, psh, qf, of, m_i, l_p, wv, n, qd,
                      (tstart + tt + 1) * 64 - qbase);
        }
    }

    float lred[2];
#pragma unroll
    for (int g = 0; g < 2; ++g) {
        float l = l_p[g];
        l += __shfl_xor(l, 16);
        l += __shfl_xor(l, 32);
        lred[g] = l;
    }

    size_t pb = ((size_t)(h * 16 + qt)) * 2 + c;
    short* op = opart + pb * (128 * 128);
#pragma unroll
    for (int g = 0; g < 2; ++g)
#pragma unroll
        for (int nb = 0; nb < 8; ++nb)
#pragma unroll
            for (int r = 0; r < 4; ++r) {
                int rl = wv * 32 + g * 16 + qd * 4 + r;
                op[rl * 128 + nb * 16 + n] = f2bf(of[g][nb][r]);
            }
    if (qd == 0) {
#pragma unroll
        for (int g = 0; g < 2; ++g) {
            int rl = wv * 32 + g * 16 + n;
            ml[pb * 256 + rl * 2] = m_i[g] * SCALE;   // pre-scaled for merge
            ml[pb * 256 + rl * 2 + 1] = lred[g];
        }
    }
}

// ---------------- 4b. merge the two k-chunk partials per q-tile ----------------
__global__ __launch_bounds__(256) void attn_merge_kernel(
    const short* __restrict__ opart, const float* __restrict__ ml,
    short* __restrict__ o) {
    int bid = blockIdx.x;             // 256: h*16 + qt
    int h = bid >> 4, qt = bid & 15;
    int tid = threadIdx.x;
    int r = tid >> 1, hf = tid & 1;   // row 0..127, dim half
    size_t pb0 = ((size_t)(h * 16 + qt)) * 2;
    size_t pb1 = pb0 + 1;
    float m0 = ml[pb0 * 256 + r * 2], l0 = ml[pb0 * 256 + r * 2 + 1];
    float m1 = ml[pb1 * 256 + r * 2], l1 = ml[pb1 * 256 + r * 2 + 1];
    float M = fmaxf(m0, m1);
    float w0 = __expf(m0 - M), w1 = __expf(m1 - M);
    float invL = 1.0f / (w0 * l0 + w1 * l1);
    int row = qt * 128 + r;
#pragma unroll
    for (int j = 0; j < 8; ++j) {
        int d0 = hf * 64 + j * 8;
        bf8_t a = *(const bf8_t*)(opart + pb0 * (128 * 128) + r * 128 + d0);
        bf8_t b = *(const bf8_t*)(opart + pb1 * (128 * 128) + r * 128 + d0);
        bf8_t e;
#pragma unroll
        for (int x = 0; x < 8; ++x)
            e[x] = f2bf((w0 * bf2f(a[x]) + w1 * bf2f(b[x])) * invL);
        *(bf8_t*)(o + (size_t)row * (NH * HD) + h * HD + d0) = e;
    }
}

// ---------------- launch ----------------
// Workspace layout (high-water 48.5 MB):
//   +0  hnb   8 MB  (prep out / gemm1 A; merge writes attn-out)
//   +8  wqb  16 MB  (gemm1 B; dead after)  -> overlaid by mid outputs:
//   +8  qbf   8 MB, +16 kbf 4 MB, +20 vtb 4 MB
//   +24 wob   8 MB  (gemm2 B)
//   +32 pB   16 MB  (gemm1 z=1 bf16 partial; dead after mid)
//   +48 mlbuf 0.5 MB
//   d_out: pA (gemm1 z=0 partial) -> opart (attn) -> final out
//   gemm2 f32 partials: p0=+8 (dead after attn), p1=+32 (dead after mid)
extern "C" void kernel_launch(void* const* d_in, const int* in_sizes, int n_in,
                              void* d_out, int out_size, void* d_ws, size_t ws_size,
                              hipStream_t stream) {
    const int* positions   = (const int*)d_in[0];
    const float* hidden    = (const float*)d_in[1];
    const float* ln_w      = (const float*)d_in[2];
    const float* w_qkv     = (const float*)d_in[3];
    const float* w_o       = (const float*)d_in[4];
    const float* q_norm_w  = (const float*)d_in[5];
    const float* k_norm_w  = (const float*)d_in[6];
    float* out = (float*)d_out;

    char* base = (char*)d_ws;
    short* hnb   = (short*)(base);
    short* wqb   = (short*)(base + ((size_t)8 << 20));
    short* qbf   = (short*)(base + ((size_t)8 << 20));
    short* kbf   = (short*)(base + ((size_t)16 << 20));
    short* vtb   = (short*)(base + ((size_t)20 << 20));
    short* wob   = (short*)(base + ((size_t)24 << 20));
    short* pB    = (short*)(base + ((size_t)32 << 20));
    float* mlbuf = (float*)(base + ((size_t)48 << 20));
    short* pA    = (short*)d_out;
    short* opart = (short*)d_out;
    float* p0    = (float*)(base + ((size_t)8 << 20));
    float* p1    = (float*)(base + ((size_t)32 << 20));

    prep_kernel<<<8192, 256, 0, stream>>>(w_qkv, wqb, w_o, wob, hidden, ln_w, hnb);
    gemm1_v7_kernel<<<dim3(16, 8, 2), 512, 0, stream>>>(hnb, wqb, pA, pB);
    mid_kernel<<<512 + 24576, 256, 0, stream>>>(
        pA, pB, vtb, qbf, kbf, q_norm_w, k_norm_w, positions);
    attn_chunk_kernel<<<512, 256, 0, stream>>>(qbf, kbf, vtb, opart, mlbuf);
    attn_merge_kernel<<<256, 256, 0, stream>>>(opart, mlbuf, hnb);
    gemm_mfma_kernel<<<dim3(16, 16, 2), 256, 0, stream>>>(
        hnb, wob, p0, p1, SEQ, NH * HD, HID);
    splitk_reduce_kernel<<<2048, 256, 0, stream>>>(p0, p1, out);
}

// Round 8
// 261.827 us; speedup vs baseline: 1.0009x; 1.0009x over previous
//
#include <hip/hip_runtime.h>
#include <hip/hip_bf16.h>
#include <math.h>

#define HID 2048
#define NH 16
#define NKV 8
#define HD 128
#define SEQ 2048
#define EPS 1e-6f
#define THETA 10000.0f
#define SCALE 0.08838834764831845f  // 128^-0.5
#define DTHR 90.50966799187809f     // 8 / SCALE: defer-max threshold in raw-score units

typedef __attribute__((ext_vector_type(8))) short bf8_t;   // 8 bf16 (4 VGPRs)
typedef __attribute__((ext_vector_type(4))) short bf4_t;   // 4 bf16 (2 VGPRs)
typedef __attribute__((ext_vector_type(4))) float f4_t;    // 4 fp32

__device__ __forceinline__ short f2bf(float f) {
    union { __hip_bfloat16 h; short s; } u;
    u.h = __float2bfloat16(f);
    return u.s;
}
__device__ __forceinline__ float bf2f(short s) {
    union { short s; __hip_bfloat16 h; } u;
    u.s = s;
    return __bfloat162float(u.h);
}
__device__ __forceinline__ bf8_t pack8(const float4& a, const float4& b) {
    bf8_t r;
    r[0] = f2bf(a.x); r[1] = f2bf(a.y); r[2] = f2bf(a.z); r[3] = f2bf(a.w);
    r[4] = f2bf(b.x); r[5] = f2bf(b.y); r[6] = f2bf(b.z); r[7] = f2bf(b.w);
    return r;
}
// async global->LDS DMA, 16 B per lane; lds dest = wave-uniform base + lane*16
__device__ __forceinline__ void gload16(const short* g, short* l) {
    __builtin_amdgcn_global_load_lds(
        (const __attribute__((address_space(1))) unsigned int*)g,
        (__attribute__((address_space(3))) unsigned int*)l, 16, 0, 0);
}

__device__ __forceinline__ float wave_reduce_sum(float v) {
#pragma unroll
    for (int off = 32; off > 0; off >>= 1) v += __shfl_xor(v, off);
    return v;
}

// ---------------- 1. fused prep: f2bf(w_qkv) | f2bf(w_o) | hidden RMSNorm ------
__global__ __launch_bounds__(256) void prep_kernel(
    const float* __restrict__ w_qkv, short* __restrict__ wqb,
    const float* __restrict__ w_o, short* __restrict__ wob,
    const float* __restrict__ x, const float* __restrict__ w,
    short* __restrict__ out) {
    int bid = blockIdx.x;
    int tid = threadIdx.x;
    if (bid < 4096) {
        int i = bid * 256 + tid;
        float4 a = *(const float4*)(w_qkv + (size_t)i * 8);
        float4 b = *(const float4*)(w_qkv + (size_t)i * 8 + 4);
        *(bf8_t*)(wqb + (size_t)i * 8) = pack8(a, b);
        return;
    }
    if (bid < 6144) {
        int i = (bid - 4096) * 256 + tid;
        float4 a = *(const float4*)(w_o + (size_t)i * 8);
        float4 b = *(const float4*)(w_o + (size_t)i * 8 + 4);
        *(bf8_t*)(wob + (size_t)i * 8) = pack8(a, b);
        return;
    }
    int row = bid - 6144;
    const float* xr = x + (size_t)row * HID;
    float4 a = *(const float4*)(xr + tid * 8);
    float4 b = *(const float4*)(xr + tid * 8 + 4);
    float ss = a.x * a.x + a.y * a.y + a.z * a.z + a.w * a.w +
               b.x * b.x + b.y * b.y + b.z * b.z + b.w * b.w;
    ss = wave_reduce_sum(ss);
    __shared__ float part[4];
    __shared__ float s_scale;
    if ((tid & 63) == 0) part[tid >> 6] = ss;
    __syncthreads();
    if (tid == 0) {
        float t = part[0] + part[1] + part[2] + part[3];
        s_scale = rsqrtf(t / (float)HID + EPS);
    }
    __syncthreads();
    float sc = s_scale;
    float4 wa = *(const float4*)(w + tid * 8);
    float4 wb = *(const float4*)(w + tid * 8 + 4);
    float4 oa = make_float4(a.x * sc * wa.x, a.y * sc * wa.y,
                            a.z * sc * wa.z, a.w * sc * wa.w);
    float4 ob = make_float4(b.x * sc * wb.x, b.y * sc * wb.y,
                            b.z * sc * wb.z, b.w * sc * wb.w);
    *(bf8_t*)(out + (size_t)row * HID + tid * 8) = pack8(oa, ob);
}

// ---------------- 2. gemm1 v8b: 256x256, 8 waves, de-lockstepped tri-buffer ----
// v8 bugfix: nbuf wrap was wrong for cur==2 (produced 4 -> OOB LDS DMA that
// clobbered SB). Pipeline logic unchanged: ONE barrier per K-tile (vmcnt(4)
// drains tile t across all waves before any wave reads it; tri-buffering
// removes the post-MFMA barrier); stage issued AFTER the barrier; two phases
// per tile {stage2 | dsread | 16 MFMA} with setprio per MFMA cluster.
#define G1_N 4096
#define G1_T 32   // K-tiles per block: 1024 / 32
__global__ __launch_bounds__(512) void gemm1_v8_kernel(
    const short* __restrict__ A, const short* __restrict__ B,
    short* __restrict__ pA, short* __restrict__ pB) {
    __shared__ short SA[3][256][32];
    __shared__ short SB[3][256][32];
    int tid = threadIdx.x;
    int w = tid >> 6, lane = tid & 63;
    int n16 = lane & 15, qd = lane >> 4;
    int m0 = blockIdx.y * 256, n0 = blockIdx.x * 256;
    int z = blockIdx.z;
    int kbeg = z ? (HID / 2) : 0;
    short* Pp = z ? pB : pA;
    int wm = (w >> 2) * 128, wn = (w & 3) * 64;

    // staging: 2 A-instr + 2 B-instr per K-tile; each instr: wave covers 16 rows
    // (4 lanes/row, chunk = lane&3 of 4x8-short chunks), rotation by (row>>1).
    size_t aBase[2], bBase[2];
#pragma unroll
    for (int it = 0; it < 2; ++it) {
        int rl = w * 32 + it * 16 + (lane >> 2);      // local row 0..255
        int c = ((lane & 3) - (rl >> 1)) & 3;         // inverse-rotated chunk
        aBase[it] = (size_t)(m0 + rl) * HID + kbeg + c * 8;
        bBase[it] = (size_t)(n0 + rl) * HID + kbeg + c * 8;
    }

    f4_t acc[8][4];
#pragma unroll
    for (int m = 0; m < 8; ++m)
#pragma unroll
        for (int nn = 0; nn < 4; ++nn) acc[m][nn] = (f4_t){0.f, 0.f, 0.f, 0.f};

    auto stageA = [&](int buf, int t) {     // half 0: A-it0 + B-it0
        int ko = t * 32;
        gload16(A + aBase[0] + ko, &SA[buf][w * 32][0]);
        gload16(B + bBase[0] + ko, &SB[buf][w * 32][0]);
    };
    auto stageB = [&](int buf, int t) {     // half 1: A-it1 + B-it1
        int ko = t * 32;
        gload16(A + aBase[1] + ko, &SA[buf][w * 32 + 16][0]);
        gload16(B + bBase[1] + ko, &SB[buf][w * 32 + 16][0]);
    };

    // prologue: tiles 0 and 1 fully staged (8 instr in flight)
    stageA(0, 0); stageB(0, 0);
    stageA(1, 1); stageB(1, 1);
    int cur = 0;
    for (int t = 0; t < G1_T; ++t) {
        // drain tile t's 4 loads (oldest); tile t+1's 4 stay in flight
        if (t < G1_T - 1) asm volatile("s_waitcnt vmcnt(4)" ::: "memory");
        else              asm volatile("s_waitcnt vmcnt(0)" ::: "memory");
        __builtin_amdgcn_s_barrier();
        asm volatile("" ::: "memory");

        int nbuf = cur + 2; if (nbuf >= 3) nbuf -= 3;   // (cur+2) % 3, fixed
        // ---- phase A: stage half0 of t+2 | read af[0..3]+bf[0..3] | 16 MFMA
        if (t + 2 < G1_T) stageA(nbuf, t + 2);
        bf8_t af[4], bfv[4];
#pragma unroll
        for (int m = 0; m < 4; ++m) {
            int row = wm + m * 16 + n16;
            af[m] = *(const bf8_t*)&SA[cur][row][((qd + (row >> 1)) & 3) * 8];
        }
#pragma unroll
        for (int nn = 0; nn < 4; ++nn) {
            int row = wn + nn * 16 + n16;
            bfv[nn] = *(const bf8_t*)&SB[cur][row][((qd + (row >> 1)) & 3) * 8];
        }
        __builtin_amdgcn_s_setprio(1);
#pragma unroll
        for (int m = 0; m < 4; ++m)
#pragma unroll
            for (int nn = 0; nn < 4; ++nn)
                acc[m][nn] = __builtin_amdgcn_mfma_f32_16x16x32_bf16(
                    af[m], bfv[nn], acc[m][nn], 0, 0, 0);
        __builtin_amdgcn_s_setprio(0);
        // ---- phase B: stage half1 of t+2 | read af[4..7] | 16 MFMA
        if (t + 2 < G1_T) stageB(nbuf, t + 2);
        bf8_t af2[4];
#pragma unroll
        for (int m = 0; m < 4; ++m) {
            int row = wm + 64 + m * 16 + n16;
            af2[m] = *(const bf8_t*)&SA[cur][row][((qd + (row >> 1)) & 3) * 8];
        }
        __builtin_amdgcn_s_setprio(1);
#pragma unroll
        for (int m = 0; m < 4; ++m)
#pragma unroll
            for (int nn = 0; nn < 4; ++nn)
                acc[m + 4][nn] = __builtin_amdgcn_mfma_f32_16x16x32_bf16(
                    af2[m], bfv[nn], acc[m + 4][nn], 0, 0, 0);
        __builtin_amdgcn_s_setprio(0);
        cur = (cur + 1) == 3 ? 0 : (cur + 1);
    }

#pragma unroll
    for (int m = 0; m < 8; ++m)
#pragma unroll
        for (int nn = 0; nn < 4; ++nn)
#pragma unroll
            for (int r = 0; r < 4; ++r) {
                int gm = m0 + wm + m * 16 + qd * 4 + r;
                int gn = n0 + wn + nn * 16 + n16;
                Pp[(size_t)gm * G1_N + gn] = f2bf(acc[m][nn][r]);
            }
}

// ---------------- 5. gemm2: 128^2 bf16 MFMA GEMM, split-K=2 f32 partials ------
__global__ __launch_bounds__(256) void gemm_mfma_kernel(
    const short* __restrict__ A, const short* __restrict__ B,
    float* __restrict__ C0, float* __restrict__ C1, int M, int N, int K) {
    __shared__ short As[128][64];
    __shared__ short Bs[128][64];
    int tid = threadIdx.x;
    int wv = tid >> 6, lane = tid & 63;
    int n16 = lane & 15, qd = lane >> 4;
    int m0 = blockIdx.y * 128, n0 = blockIdx.x * 128;
    int wm = (wv >> 1) * 64, wn = (wv & 1) * 64;
    int sr8 = lane >> 3, slot = lane & 7;

    int z = blockIdx.z;
    int kbeg = z ? (K >> 1) : 0;
    int kend = z ? K : (K >> 1);
    float* Cf = z ? C1 : C0;

    size_t ainv[4], binv[4];
#pragma unroll
    for (int it = 0; it < 4; ++it) {
        int row = wv * 32 + it * 8 + sr8;
        int chunk = (slot - row) & 7;
        ainv[it] = (size_t)(m0 + row) * K + chunk * 8;
        binv[it] = (size_t)(n0 + row) * K + chunk * 8;
    }

    f4_t acc[4][4];
#pragma unroll
    for (int i = 0; i < 4; ++i)
#pragma unroll
        for (int j = 0; j < 4; ++j) acc[i][j] = (f4_t){0.f, 0.f, 0.f, 0.f};

    for (int k0 = kbeg; k0 < kend; k0 += 64) {
        __syncthreads();
#pragma unroll
        for (int it = 0; it < 4; ++it) {
            gload16(A + ainv[it] + k0, &As[wv * 32 + it * 8][0]);
            gload16(B + binv[it] + k0, &Bs[wv * 32 + it * 8][0]);
        }
        __syncthreads();

        bf8_t af[4][2], bf[4][2];
#pragma unroll
        for (int t = 0; t < 4; ++t)
#pragma unroll
            for (int ks = 0; ks < 2; ++ks) {
                int ar = wm + t * 16 + n16;
                af[t][ks] = *(const bf8_t*)&As[ar][(((ks * 4 + qd) + ar) & 7) * 8];
                int br = wn + t * 16 + n16;
                bf[t][ks] = *(const bf8_t*)&Bs[br][(((ks * 4 + qd) + br) & 7) * 8];
            }
#pragma unroll
        for (int ks = 0; ks < 2; ++ks)
#pragma unroll
            for (int mt = 0; mt < 4; ++mt)
#pragma unroll
                for (int nt = 0; nt < 4; ++nt)
                    acc[mt][nt] = __builtin_amdgcn_mfma_f32_16x16x32_bf16(
                        af[mt][ks], bf[nt][ks], acc[mt][nt], 0, 0, 0);
    }

#pragma unroll
    for (int mt = 0; mt < 4; ++mt)
#pragma unroll
        for (int nt = 0; nt < 4; ++nt)
#pragma unroll
            for (int r = 0; r < 4; ++r) {
                int gm = m0 + wm + mt * 16 + qd * 4 + r;
                int gn = n0 + wn + nt * 16 + n16;
                Cf[(size_t)gm * N + gn] = acc[mt][nt][r];
            }
}

// ---------------- 5b. split-K reduce: out = P0 + P1 (HBM-bound) --------
__global__ __launch_bounds__(256) void splitk_reduce_kernel(
    const float* __restrict__ p0, const float* __restrict__ p1,
    float* __restrict__ o) {
    size_t i = ((size_t)blockIdx.x * 256 + threadIdx.x) * 8;
    float4 a0 = *(const float4*)(p0 + i);
    float4 a1 = *(const float4*)(p0 + i + 4);
    float4 b0 = *(const float4*)(p1 + i);
    float4 b1 = *(const float4*)(p1 + i + 4);
    *(float4*)(o + i) =
        make_float4(a0.x + b0.x, a0.y + b0.y, a0.z + b0.z, a0.w + b0.w);
    *(float4*)(o + i + 4) =
        make_float4(a1.x + b1.x, a1.y + b1.y, a1.z + b1.z, a1.w + b1.w);
}

// ---------------- 3. fused mid: gemm1 partial-add + V transpose | q/k RMSNorm+RoPE
__global__ __launch_bounds__(256) void mid_kernel(
    const short* __restrict__ pA, const short* __restrict__ pB,
    short* __restrict__ vt, short* __restrict__ q, short* __restrict__ k,
    const float* __restrict__ qw, const float* __restrict__ kw,
    const int* __restrict__ pos) {
    int bid = blockIdx.x;
    int tid = threadIdx.x;
    if (bid < 512) {  // ---- V transpose, 64x64 tile ----
        __shared__ short t[64][64];
        int s0 = (bid & 31) * 64, d0 = (bid >> 5) * 64;
        int sl = tid >> 3, ch = tid & 7;
#pragma unroll
        for (int it = 0; it < 2; ++it) {
            int s_local = it * 32 + sl;
            size_t off = (size_t)(s0 + s_local) * 4096 + 3072 + d0 + ch * 8;
            bf8_t a = *(const bf8_t*)(pA + off);
            bf8_t b = *(const bf8_t*)(pB + off);
            bf8_t vv;
#pragma unroll
            for (int j = 0; j < 8; ++j) vv[j] = f2bf(bf2f(a[j]) + bf2f(b[j]));
            *(bf8_t*)&t[s_local][((ch + s_local) & 7) * 8] = vv;
        }
        __syncthreads();
#pragma unroll
        for (int it = 0; it < 2; ++it) {
            int d_local = it * 32 + sl;
            int sbase = ch * 8;
            bf8_t o;
#pragma unroll
            for (int j = 0; j < 8; ++j) {
                int s = sbase + j;
                o[j] = t[s][(((d_local >> 3) + s) & 7) * 8 + (d_local & 7)];
            }
            *(bf8_t*)(vt + (size_t)(d0 + d_local) * SEQ + s0 + sbase) = o;
        }
        return;
    }
    // ---- q/k partial-add + RMSNorm + RoPE: two 128-thread units per block ----
    int u = (bid - 512) * 2 + (tid >> 7);
    int ui = tid >> 7, d = tid & 127;
    int s = u / 24, hh = u % 24;
    int col;
    short* optr;
    const float* w;
    if (hh < NH) {
        col = hh * HD + d;
        optr = q + (size_t)s * (NH * HD) + hh * HD;
        w = qw;
    } else {
        col = 2048 + (hh - NH) * HD + d;
        optr = k + (size_t)s * (NKV * HD) + (hh - NH) * HD;
        w = kw;
    }
    size_t poff = (size_t)s * 4096 + col;
    float x = bf2f(pA[poff]) + bf2f(pB[poff]);
    float ss = wave_reduce_sum(x * x);
    __shared__ float part[2][2];
    if ((d & 63) == 0) part[ui][d >> 6] = ss;
    __syncthreads();
    float tot = part[ui][0] + part[ui][1];
    float xn = x * rsqrtf(tot / (float)HD + EPS) * w[d];
    __shared__ float sh[2][HD];
    sh[ui][d] = xn;
    __syncthreads();
    int j = d & 63;
    float inv = __expf((float)j * -0.14391156831f);  // 10000^(-j/64), fast exp
    float fr = (float)pos[s] * inv;
    float sn, cs;
    __sincosf(fr, &sn, &cs);
    float o;
    if (d < 64)
        o = xn * cs - sh[ui][d + 64] * sn;
    else
        o = xn * cs + sh[ui][d - 64] * sn;
    optr[d] = f2bf(o);
}

// ---------------- 4. MFMA flash attention v6: swapped-QK^T, lane-local rows ----
__device__ __forceinline__ void attn_stage(
    short (&kb)[64][128], short (&vb)[128][64],
    const short* __restrict__ kg, const short* __restrict__ vg,
    int t0, const int (&kinv)[4], const int (&vinv)[4], int wv) {
#pragma unroll
    for (int it = 0; it < 4; ++it) {
        gload16(kg + (size_t)t0 * (NKV * HD) + kinv[it], &kb[wv * 16 + it * 4][0]);
        gload16(vg + t0 + vinv[it], &vb[wv * 32 + it * 8][0]);
    }
}

__device__ __forceinline__ void attn_tile(
    const short (&kb)[64][128], const short (&vb)[128][64],
    short (&psh)[4][2][16][64],
    const bf8_t (&qf)[2][4], f4_t (&of)[2][8],
    float (&m_i)[2], float (&l_p)[2],
    int wv, int n, int qd, int koff) {
    f4_t sc[2][4];
#pragma unroll
    for (int g = 0; g < 2; ++g)
#pragma unroll
        for (int kk = 0; kk < 4; ++kk) sc[g][kk] = (f4_t){0.f, 0.f, 0.f, 0.f};
    __builtin_amdgcn_s_setprio(1);
#pragma unroll
    for (int kk = 0; kk < 4; ++kk) {
        int key = kk * 16 + n;
#pragma unroll
        for (int ks = 0; ks < 4; ++ks) {
            bf8_t kf = *(const bf8_t*)&kb[key][(((ks * 4 + qd) + key) & 15) * 8];
            sc[0][kk] = __builtin_amdgcn_mfma_f32_16x16x32_bf16(kf, qf[0][ks], sc[0][kk], 0, 0, 0);
            sc[1][kk] = __builtin_amdgcn_mfma_f32_16x16x32_bf16(kf, qf[1][ks], sc[1][kk], 0, 0, 0);
        }
    }
    __builtin_amdgcn_s_setprio(0);
#pragma unroll
    for (int g = 0; g < 2; ++g) {
        int rows0 = wv * 32 + g * 16;
        int qrow = rows0 + n;
        if (koff + 63 > rows0) {
#pragma unroll
            for (int kk = 0; kk < 4; ++kk)
#pragma unroll
                for (int r = 0; r < 4; ++r)
                    if (koff + kk * 16 + qd * 4 + r > qrow) sc[g][kk][r] = -1e30f;
        }
        float m01 = fmaxf(fmaxf(fmaxf(sc[g][0][0], sc[g][0][1]), fmaxf(sc[g][0][2], sc[g][0][3])),
                          fmaxf(fmaxf(sc[g][1][0], sc[g][1][1]), fmaxf(sc[g][1][2], sc[g][1][3])));
        float m23 = fmaxf(fmaxf(fmaxf(sc[g][2][0], sc[g][2][1]), fmaxf(sc[g][2][2], sc[g][2][3])),
                          fmaxf(fmaxf(sc[g][3][0], sc[g][3][1]), fmaxf(sc[g][3][2], sc[g][3][3])));
        float mx = fmaxf(m01, m23);
        mx = fmaxf(mx, __shfl_xor(mx, 16));
        mx = fmaxf(mx, __shfl_xor(mx, 32));
        if (!__all(mx <= m_i[g] + DTHR)) {
            float mnew = fmaxf(m_i[g], mx);
            float al = __expf((m_i[g] - mnew) * SCALE);
            m_i[g] = mnew;
            l_p[g] *= al;
#pragma unroll
            for (int r = 0; r < 4; ++r) {
                float alr = __shfl(al, qd * 4 + r);
#pragma unroll
                for (int nb = 0; nb < 8; ++nb) of[g][nb][r] *= alr;
            }
        }
        float mcur = m_i[g];
        float lsum = 0.f;
#pragma unroll
        for (int kk = 0; kk < 4; ++kk) {
            bf4_t pk;
#pragma unroll
            for (int r = 0; r < 4; ++r) {
                float p = __expf((sc[g][kk][r] - mcur) * SCALE);
                lsum += p;
                pk[r] = f2bf(p);
            }
            *(bf4_t*)&psh[wv][g][n][(kk * 16 + qd * 4 + n * 8) & 63] = pk;
        }
        l_p[g] += lsum;
    }
    __builtin_amdgcn_wave_barrier();  // psh write->read, same wave (in-order LDS)
    __builtin_amdgcn_s_setprio(1);
#pragma unroll
    for (int ks2 = 0; ks2 < 2; ++ks2) {
        bf8_t pf0 = *(const bf8_t*)&psh[wv][0][n][((ks2 * 32 + qd * 8) + n * 8) & 63];
        bf8_t pf1 = *(const bf8_t*)&psh[wv][1][n][((ks2 * 32 + qd * 8) + n * 8) & 63];
#pragma unroll
        for (int nb = 0; nb < 8; ++nb) {
            int dim = nb * 16 + n;
            bf8_t vf = *(const bf8_t*)&vb[dim][(((ks2 * 4 + qd) + dim) & 7) * 8];
            of[0][nb] = __builtin_amdgcn_mfma_f32_16x16x32_bf16(pf0, vf, of[0][nb], 0, 0, 0);
            of[1][nb] = __builtin_amdgcn_mfma_f32_16x16x32_bf16(pf1, vf, of[1][nb], 0, 0, 0);
        }
    }
    __builtin_amdgcn_s_setprio(0);
}

__global__ __launch_bounds__(256, 2) void attn_chunk_kernel(
    const short* __restrict__ q, const short* __restrict__ k,
    const short* __restrict__ vt, short* __restrict__ opart,
    float* __restrict__ ml) {
    __shared__ short kbufA[64][128], kbufB[64][128];
    __shared__ short vbufA[128][64], vbufB[128][64];
    __shared__ short psh[4][2][16][64];   // total LDS = 80 KB -> 2 blocks/CU

    int tid = threadIdx.x;
    int wv = tid >> 6, lane = tid & 63;
    int n = lane & 15, qd = lane >> 4;

    int i = blockIdx.x;               // 512 blocks
    int hs = i >> 8, p = i & 255;
    int h = p >> 4;
    int qt = hs ? (p & 15) : (15 - (p & 15));
    int c = hs;
    int qbase = qt * 128;
    int tstart = c ? (qt + 1) : 0;
    int tcount = qt + 1;
    int kvh = h >> 1;

    int kinv[4], vinv[4];
#pragma unroll
    for (int it = 0; it < 4; ++it) {
        int key = wv * 16 + it * 4 + (lane >> 4);
        int ck = ((lane & 15) - key) & 15;
        kinv[it] = key * (NKV * HD) + kvh * HD + ck * 8;
        int dim = wv * 32 + it * 8 + (lane >> 3);
        int cv = ((lane & 7) - dim) & 7;
        vinv[it] = (kvh * HD + dim) * SEQ + cv * 8;
    }

    bf8_t qf[2][4];
#pragma unroll
    for (int g = 0; g < 2; ++g) {
        const short* qp =
            q + (size_t)(qbase + wv * 32 + g * 16 + n) * (NH * HD) + h * HD + qd * 8;
#pragma unroll
        for (int ks = 0; ks < 4; ++ks) qf[g][ks] = *(const bf8_t*)(qp + ks * 32);
    }

    f4_t of[2][8];
#pragma unroll
    for (int g = 0; g < 2; ++g)
#pragma unroll
        for (int x = 0; x < 8; ++x) of[g][x] = (f4_t){0.f, 0.f, 0.f, 0.f};
    float m_i[2] = {-1e30f, -1e30f};
    float l_p[2] = {0.f, 0.f};

    attn_stage(kbufA, vbufA, k, vt, tstart * 64, kinv, vinv, wv);
    for (int tt = 0; tt < tcount; tt += 2) {
        __syncthreads();  // drains DMA for tile tt (issued a full tile ago)
        if (tt + 1 < tcount)
            attn_stage(kbufB, vbufB, k, vt, (tstart + tt + 1) * 64, kinv, vinv, wv);
        attn_tile(kbufA, vbufA, psh, qf, of, m_i, l_p, wv, n, qd,
                  (tstart + tt) * 64 - qbase);
        if (tt + 1 < tcount) {
            __syncthreads();
            if (tt + 2 < tcount)
                attn_stage(kbufA, vbufA, k, vt, (tstart + tt + 2) * 64, kinv, vinv, wv);
            attn_tile(kbufB, vbufB, psh, qf, of, m_i, l_p, wv, n, qd,
                      (tstart + tt + 1) * 64 - qbase);
        }
    }

    float lred[2];
#pragma unroll
    for (int g = 0; g < 2; ++g) {
        float l = l_p[g];
        l += __shfl_xor(l, 16);
        l += __shfl_xor(l, 32);
        lred[g] = l;
    }

    size_t pb = ((size_t)(h * 16 + qt)) * 2 + c;
    short* op = opart + pb * (128 * 128);
#pragma unroll
    for (int g = 0; g < 2; ++g)
#pragma unroll
        for (int nb = 0; nb < 8; ++nb)
#pragma unroll
            for (int r = 0; r < 4; ++r) {
                int rl = wv * 32 + g * 16 + qd * 4 + r;
                op[rl * 128 + nb * 16 + n] = f2bf(of[g][nb][r]);
            }
    if (qd == 0) {
#pragma unroll
        for (int g = 0; g < 2; ++g) {
            int rl = wv * 32 + g * 16 + n;
            ml[pb * 256 + rl * 2] = m_i[g] * SCALE;   // pre-scaled for merge
            ml[pb * 256 + rl * 2 + 1] = lred[g];
        }
    }
}

// ---------------- 4b. merge the two k-chunk partials per q-tile ----------------
__global__ __launch_bounds__(256) void attn_merge_kernel(
    const short* __restrict__ opart, const float* __restrict__ ml,
    short* __restrict__ o) {
    int bid = blockIdx.x;             // 256: h*16 + qt
    int h = bid >> 4, qt = bid & 15;
    int tid = threadIdx.x;
    int r = tid >> 1, hf = tid & 1;   // row 0..127, dim half
    size_t pb0 = ((size_t)(h * 16 + qt)) * 2;
    size_t pb1 = pb0 + 1;
    float m0 = ml[pb0 * 256 + r * 2], l0 = ml[pb0 * 256 + r * 2 + 1];
    float m1 = ml[pb1 * 256 + r * 2], l1 = ml[pb1 * 256 + r * 2 + 1];
    float M = fmaxf(m0, m1);
    float w0 = __expf(m0 - M), w1 = __expf(m1 - M);
    float invL = 1.0f / (w0 * l0 + w1 * l1);
    int row = qt * 128 + r;
#pragma unroll
    for (int j = 0; j < 8; ++j) {
        int d0 = hf * 64 + j * 8;
        bf8_t a = *(const bf8_t*)(opart + pb0 * (128 * 128) + r * 128 + d0);
        bf8_t b = *(const bf8_t*)(opart + pb1 * (128 * 128) + r * 128 + d0);
        bf8_t e;
#pragma unroll
        for (int x = 0; x < 8; ++x)
            e[x] = f2bf((w0 * bf2f(a[x]) + w1 * bf2f(b[x])) * invL);
        *(bf8_t*)(o + (size_t)row * (NH * HD) + h * HD + d0) = e;
    }
}

// ---------------- launch ----------------
// Workspace layout (high-water 48.5 MB):
//   +0  hnb   8 MB  (prep out / gemm1 A; merge writes attn-out)
//   +8  wqb  16 MB  (gemm1 B; dead after)  -> overlaid by mid outputs:
//   +8  qbf   8 MB, +16 kbf 4 MB, +20 vtb 4 MB
//   +24 wob   8 MB  (gemm2 B)
//   +32 pB   16 MB  (gemm1 z=1 bf16 partial; dead after mid)
//   +48 mlbuf 0.5 MB
//   d_out: pA (gemm1 z=0 partial) -> opart (attn) -> final out
//   gemm2 f32 partials: p0=+8 (dead after attn), p1=+32 (dead after mid)
extern "C" void kernel_launch(void* const* d_in, const int* in_sizes, int n_in,
                              void* d_out, int out_size, void* d_ws, size_t ws_size,
                              hipStream_t stream) {
    const int* positions   = (const int*)d_in[0];
    const float* hidden    = (const float*)d_in[1];
    const float* ln_w      = (const float*)d_in[2];
    const float* w_qkv     = (const float*)d_in[3];
    const float* w_o       = (const float*)d_in[4];
    const float* q_norm_w  = (const float*)d_in[5];
    const float* k_norm_w  = (const float*)d_in[6];
    float* out = (float*)d_out;

    char* base = (char*)d_ws;
    short* hnb   = (short*)(base);
    short* wqb   = (short*)(base + ((size_t)8 << 20));
    short* qbf   = (short*)(base + ((size_t)8 << 20));
    short* kbf   = (short*)(base + ((size_t)16 << 20));
    short* vtb   = (short*)(base + ((size_t)20 << 20));
    short* wob   = (short*)(base + ((size_t)24 << 20));
    short* pB    = (short*)(base + ((size_t)32 << 20));
    float* mlbuf = (float*)(base + ((size_t)48 << 20));
    short* pA    = (short*)d_out;
    short* opart = (short*)d_out;
    float* p0    = (float*)(base + ((size_t)8 << 20));
    float* p1    = (float*)(base + ((size_t)32 << 20));

    prep_kernel<<<8192, 256, 0, stream>>>(w_qkv, wqb, w_o, wob, hidden, ln_w, hnb);
    gemm1_v8_kernel<<<dim3(16, 8, 2), 512, 0, stream>>>(hnb, wqb, pA, pB);
    mid_kernel<<<512 + 24576, 256, 0, stream>>>(
        pA, pB, vtb, qbf, kbf, q_norm_w, k_norm_w, positions);
    attn_chunk_kernel<<<512, 256, 0, stream>>>(qbf, kbf, vtb, opart, mlbuf);
    attn_merge_kernel<<<256, 256, 0, stream>>>(opart, mlbuf, hnb);
    gemm_mfma_kernel<<<dim3(16, 16, 2), 256, 0, stream>>>(
        hnb, wob, p0, p1, SEQ, NH * HD, HID);
    splitk_reduce_kernel<<<2048, 256, 0, stream>>>(p0, p1, out);
}

// Round 9
// 241.222 us; speedup vs baseline: 1.0864x; 1.0854x over previous
//
#include <hip/hip_runtime.h>
#include <hip/hip_bf16.h>
#include <math.h>

#define HID 2048
#define NH 16
#define NKV 8
#define HD 128
#define SEQ 2048
#define EPS 1e-6f
#define THETA 10000.0f
#define SCALE 0.08838834764831845f  // 128^-0.5
#define DTHR 90.50966799187809f     // 8 / SCALE: defer-max threshold in raw-score units

typedef __attribute__((ext_vector_type(8))) short bf8_t;   // 8 bf16 (4 VGPRs)
typedef __attribute__((ext_vector_type(4))) short bf4_t;   // 4 bf16 (2 VGPRs)
typedef __attribute__((ext_vector_type(4))) float f4_t;    // 4 fp32

__device__ __forceinline__ short f2bf(float f) {
    union { __hip_bfloat16 h; short s; } u;
    u.h = __float2bfloat16(f);
    return u.s;
}
__device__ __forceinline__ float bf2f(short s) {
    union { short s; __hip_bfloat16 h; } u;
    u.s = s;
    return __bfloat162float(u.h);
}
__device__ __forceinline__ bf8_t pack8(const float4& a, const float4& b) {
    bf8_t r;
    r[0] = f2bf(a.x); r[1] = f2bf(a.y); r[2] = f2bf(a.z); r[3] = f2bf(a.w);
    r[4] = f2bf(b.x); r[5] = f2bf(b.y); r[6] = f2bf(b.z); r[7] = f2bf(b.w);
    return r;
}
// async global->LDS DMA, 16 B per lane; lds dest = wave-uniform base + lane*16
__device__ __forceinline__ void gload16(const short* g, short* l) {
    __builtin_amdgcn_global_load_lds(
        (const __attribute__((address_space(1))) unsigned int*)g,
        (__attribute__((address_space(3))) unsigned int*)l, 16, 0, 0);
}

__device__ __forceinline__ float wave_reduce_sum(float v) {
#pragma unroll
    for (int off = 32; off > 0; off >>= 1) v += __shfl_xor(v, off);
    return v;
}

// ---------------- 1. fused prep: f2bf(w_qkv) | f2bf(w_o) | hidden RMSNorm ------
__global__ __launch_bounds__(256) void prep_kernel(
    const float* __restrict__ w_qkv, short* __restrict__ wqb,
    const float* __restrict__ w_o, short* __restrict__ wob,
    const float* __restrict__ x, const float* __restrict__ w,
    short* __restrict__ out) {
    int bid = blockIdx.x;
    int tid = threadIdx.x;
    if (bid < 4096) {
        int i = bid * 256 + tid;
        float4 a = *(const float4*)(w_qkv + (size_t)i * 8);
        float4 b = *(const float4*)(w_qkv + (size_t)i * 8 + 4);
        *(bf8_t*)(wqb + (size_t)i * 8) = pack8(a, b);
        return;
    }
    if (bid < 6144) {
        int i = (bid - 4096) * 256 + tid;
        float4 a = *(const float4*)(w_o + (size_t)i * 8);
        float4 b = *(const float4*)(w_o + (size_t)i * 8 + 4);
        *(bf8_t*)(wob + (size_t)i * 8) = pack8(a, b);
        return;
    }
    int row = bid - 6144;
    const float* xr = x + (size_t)row * HID;
    float4 a = *(const float4*)(xr + tid * 8);
    float4 b = *(const float4*)(xr + tid * 8 + 4);
    float ss = a.x * a.x + a.y * a.y + a.z * a.z + a.w * a.w +
               b.x * b.x + b.y * b.y + b.z * b.z + b.w * b.w;
    ss = wave_reduce_sum(ss);
    __shared__ float part[4];
    __shared__ float s_scale;
    if ((tid & 63) == 0) part[tid >> 6] = ss;
    __syncthreads();
    if (tid == 0) {
        float t = part[0] + part[1] + part[2] + part[3];
        s_scale = rsqrtf(t / (float)HID + EPS);
    }
    __syncthreads();
    float sc = s_scale;
    float4 wa = *(const float4*)(w + tid * 8);
    float4 wb = *(const float4*)(w + tid * 8 + 4);
    float4 oa = make_float4(a.x * sc * wa.x, a.y * sc * wa.y,
                            a.z * sc * wa.z, a.w * sc * wa.w);
    float4 ob = make_float4(b.x * sc * wb.x, b.y * sc * wb.y,
                            b.z * sc * wb.z, b.w * sc * wb.w);
    *(bf8_t*)(out + (size_t)row * HID + tid * 8) = pack8(oa, ob);
}

// ---------------- 2. gemm1 v8b: 256x256, 8 waves, de-lockstepped tri-buffer ----
#define G1_N 4096
#define G1_T 32   // K-tiles per block: 1024 / 32
__global__ __launch_bounds__(512) void gemm1_v8_kernel(
    const short* __restrict__ A, const short* __restrict__ B,
    short* __restrict__ pA, short* __restrict__ pB) {
    __shared__ short SA[3][256][32];
    __shared__ short SB[3][256][32];
    int tid = threadIdx.x;
    int w = tid >> 6, lane = tid & 63;
    int n16 = lane & 15, qd = lane >> 4;
    int m0 = blockIdx.y * 256, n0 = blockIdx.x * 256;
    int z = blockIdx.z;
    int kbeg = z ? (HID / 2) : 0;
    short* Pp = z ? pB : pA;
    int wm = (w >> 2) * 128, wn = (w & 3) * 64;

    size_t aBase[2], bBase[2];
#pragma unroll
    for (int it = 0; it < 2; ++it) {
        int rl = w * 32 + it * 16 + (lane >> 2);      // local row 0..255
        int c = ((lane & 3) - (rl >> 1)) & 3;         // inverse-rotated chunk
        aBase[it] = (size_t)(m0 + rl) * HID + kbeg + c * 8;
        bBase[it] = (size_t)(n0 + rl) * HID + kbeg + c * 8;
    }

    f4_t acc[8][4];
#pragma unroll
    for (int m = 0; m < 8; ++m)
#pragma unroll
        for (int nn = 0; nn < 4; ++nn) acc[m][nn] = (f4_t){0.f, 0.f, 0.f, 0.f};

    auto stageA = [&](int buf, int t) {     // half 0: A-it0 + B-it0
        int ko = t * 32;
        gload16(A + aBase[0] + ko, &SA[buf][w * 32][0]);
        gload16(B + bBase[0] + ko, &SB[buf][w * 32][0]);
    };
    auto stageB = [&](int buf, int t) {     // half 1: A-it1 + B-it1
        int ko = t * 32;
        gload16(A + aBase[1] + ko, &SA[buf][w * 32 + 16][0]);
        gload16(B + bBase[1] + ko, &SB[buf][w * 32 + 16][0]);
    };

    // prologue: tiles 0 and 1 fully staged (8 instr in flight)
    stageA(0, 0); stageB(0, 0);
    stageA(1, 1); stageB(1, 1);
    int cur = 0;
    for (int t = 0; t < G1_T; ++t) {
        // drain tile t's 4 loads (oldest); tile t+1's 4 stay in flight
        if (t < G1_T - 1) asm volatile("s_waitcnt vmcnt(4)" ::: "memory");
        else              asm volatile("s_waitcnt vmcnt(0)" ::: "memory");
        __builtin_amdgcn_s_barrier();
        asm volatile("" ::: "memory");

        int nbuf = cur + 2; if (nbuf >= 3) nbuf -= 3;   // (cur+2) % 3
        // ---- phase A: stage half0 of t+2 | read af[0..3]+bf[0..3] | 16 MFMA
        if (t + 2 < G1_T) stageA(nbuf, t + 2);
        bf8_t af[4], bfv[4];
#pragma unroll
        for (int m = 0; m < 4; ++m) {
            int row = wm + m * 16 + n16;
            af[m] = *(const bf8_t*)&SA[cur][row][((qd + (row >> 1)) & 3) * 8];
        }
#pragma unroll
        for (int nn = 0; nn < 4; ++nn) {
            int row = wn + nn * 16 + n16;
            bfv[nn] = *(const bf8_t*)&SB[cur][row][((qd + (row >> 1)) & 3) * 8];
        }
        __builtin_amdgcn_s_setprio(1);
#pragma unroll
        for (int m = 0; m < 4; ++m)
#pragma unroll
            for (int nn = 0; nn < 4; ++nn)
                acc[m][nn] = __builtin_amdgcn_mfma_f32_16x16x32_bf16(
                    af[m], bfv[nn], acc[m][nn], 0, 0, 0);
        __builtin_amdgcn_s_setprio(0);
        // ---- phase B: stage half1 of t+2 | read af[4..7] | 16 MFMA
        if (t + 2 < G1_T) stageB(nbuf, t + 2);
        bf8_t af2[4];
#pragma unroll
        for (int m = 0; m < 4; ++m) {
            int row = wm + 64 + m * 16 + n16;
            af2[m] = *(const bf8_t*)&SA[cur][row][((qd + (row >> 1)) & 3) * 8];
        }
        __builtin_amdgcn_s_setprio(1);
#pragma unroll
        for (int m = 0; m < 4; ++m)
#pragma unroll
            for (int nn = 0; nn < 4; ++nn)
                acc[m + 4][nn] = __builtin_amdgcn_mfma_f32_16x16x32_bf16(
                    af2[m], bfv[nn], acc[m + 4][nn], 0, 0, 0);
        __builtin_amdgcn_s_setprio(0);
        cur = (cur + 1) == 3 ? 0 : (cur + 1);
    }

#pragma unroll
    for (int m = 0; m < 8; ++m)
#pragma unroll
        for (int nn = 0; nn < 4; ++nn)
#pragma unroll
            for (int r = 0; r < 4; ++r) {
                int gm = m0 + wm + m * 16 + qd * 4 + r;
                int gn = n0 + wn + nn * 16 + n16;
                Pp[(size_t)gm * G1_N + gn] = f2bf(acc[m][nn][r]);
            }
}

// ---------------- 5. gemm2: 128^2 bf16 MFMA GEMM, split-K=2 bf16 partials ------
// Partials now bf16 (epilogue WRITE 32->16 MB; r5 profile showed the f32
// epilogue drain made gemm2 ~50 us at only 343 TF).
__global__ __launch_bounds__(256) void gemm_mfma_kernel(
    const short* __restrict__ A, const short* __restrict__ B,
    short* __restrict__ P0, short* __restrict__ P1, int M, int N, int K) {
    __shared__ short As[128][64];
    __shared__ short Bs[128][64];
    int tid = threadIdx.x;
    int wv = tid >> 6, lane = tid & 63;
    int n16 = lane & 15, qd = lane >> 4;
    int m0 = blockIdx.y * 128, n0 = blockIdx.x * 128;
    int wm = (wv >> 1) * 64, wn = (wv & 1) * 64;
    int sr8 = lane >> 3, slot = lane & 7;

    int z = blockIdx.z;
    int kbeg = z ? (K >> 1) : 0;
    int kend = z ? K : (K >> 1);
    short* Pp = z ? P1 : P0;

    size_t ainv[4], binv[4];
#pragma unroll
    for (int it = 0; it < 4; ++it) {
        int row = wv * 32 + it * 8 + sr8;
        int chunk = (slot - row) & 7;
        ainv[it] = (size_t)(m0 + row) * K + chunk * 8;
        binv[it] = (size_t)(n0 + row) * K + chunk * 8;
    }

    f4_t acc[4][4];
#pragma unroll
    for (int i = 0; i < 4; ++i)
#pragma unroll
        for (int j = 0; j < 4; ++j) acc[i][j] = (f4_t){0.f, 0.f, 0.f, 0.f};

    for (int k0 = kbeg; k0 < kend; k0 += 64) {
        __syncthreads();
#pragma unroll
        for (int it = 0; it < 4; ++it) {
            gload16(A + ainv[it] + k0, &As[wv * 32 + it * 8][0]);
            gload16(B + binv[it] + k0, &Bs[wv * 32 + it * 8][0]);
        }
        __syncthreads();

        bf8_t af[4][2], bf[4][2];
#pragma unroll
        for (int t = 0; t < 4; ++t)
#pragma unroll
            for (int ks = 0; ks < 2; ++ks) {
                int ar = wm + t * 16 + n16;
                af[t][ks] = *(const bf8_t*)&As[ar][(((ks * 4 + qd) + ar) & 7) * 8];
                int br = wn + t * 16 + n16;
                bf[t][ks] = *(const bf8_t*)&Bs[br][(((ks * 4 + qd) + br) & 7) * 8];
            }
#pragma unroll
        for (int ks = 0; ks < 2; ++ks)
#pragma unroll
            for (int mt = 0; mt < 4; ++mt)
#pragma unroll
                for (int nt = 0; nt < 4; ++nt)
                    acc[mt][nt] = __builtin_amdgcn_mfma_f32_16x16x32_bf16(
                        af[mt][ks], bf[nt][ks], acc[mt][nt], 0, 0, 0);
    }

#pragma unroll
    for (int mt = 0; mt < 4; ++mt)
#pragma unroll
        for (int nt = 0; nt < 4; ++nt)
#pragma unroll
            for (int r = 0; r < 4; ++r) {
                int gm = m0 + wm + mt * 16 + qd * 4 + r;
                int gn = n0 + wn + nt * 16 + n16;
                Pp[(size_t)gm * N + gn] = f2bf(acc[mt][nt][r]);
            }
}

// ---------------- 5b. split-K reduce: out = P0 + P1 (bf16 in, f32 out) --------
__global__ __launch_bounds__(256) void splitk_reduce_kernel(
    const short* __restrict__ p0, const short* __restrict__ p1,
    float* __restrict__ o) {
    size_t i = ((size_t)blockIdx.x * 256 + threadIdx.x) * 8;
    bf8_t a = *(const bf8_t*)(p0 + i);
    bf8_t b = *(const bf8_t*)(p1 + i);
    float4 o0, o1;
    o0.x = bf2f(a[0]) + bf2f(b[0]); o0.y = bf2f(a[1]) + bf2f(b[1]);
    o0.z = bf2f(a[2]) + bf2f(b[2]); o0.w = bf2f(a[3]) + bf2f(b[3]);
    o1.x = bf2f(a[4]) + bf2f(b[4]); o1.y = bf2f(a[5]) + bf2f(b[5]);
    o1.z = bf2f(a[6]) + bf2f(b[6]); o1.w = bf2f(a[7]) + bf2f(b[7]);
    *(float4*)(o + i) = o0;
    *(float4*)(o + i + 4) = o1;
}

// ---------------- 3. fused mid v2: partial-add + V transpose | q/k norm+RoPE ----
// q/k path rebuilt: 8 lanes/row, each lane owns d=[lr*8..lr*8+7] AND its RoPE
// partner d+64 (16 elems) -> rotation is thread-local; RMSNorm reduce = 3
// shfl_xor over the 8-lane row group. No LDS, no barriers. 32 rows/block ->
// 1536 blocks (was 24576 128-thread units).
__global__ __launch_bounds__(256) void mid_kernel(
    const short* __restrict__ pA, const short* __restrict__ pB,
    short* __restrict__ vt, short* __restrict__ q, short* __restrict__ k,
    const float* __restrict__ qw, const float* __restrict__ kw,
    const int* __restrict__ pos) {
    int bid = blockIdx.x;
    int tid = threadIdx.x;
    if (bid < 512) {  // ---- V transpose, 64x64 tile ----
        __shared__ short t[64][64];
        int s0 = (bid & 31) * 64, d0 = (bid >> 5) * 64;
        int sl = tid >> 3, ch = tid & 7;
#pragma unroll
        for (int it = 0; it < 2; ++it) {
            int s_local = it * 32 + sl;
            size_t off = (size_t)(s0 + s_local) * 4096 + 3072 + d0 + ch * 8;
            bf8_t a = *(const bf8_t*)(pA + off);
            bf8_t b = *(const bf8_t*)(pB + off);
            bf8_t vv;
#pragma unroll
            for (int j = 0; j < 8; ++j) vv[j] = f2bf(bf2f(a[j]) + bf2f(b[j]));
            *(bf8_t*)&t[s_local][((ch + s_local) & 7) * 8] = vv;
        }
        __syncthreads();
#pragma unroll
        for (int it = 0; it < 2; ++it) {
            int d_local = it * 32 + sl;
            int sbase = ch * 8;
            bf8_t o;
#pragma unroll
            for (int j = 0; j < 8; ++j) {
                int s = sbase + j;
                o[j] = t[s][(((d_local >> 3) + s) & 7) * 8 + (d_local & 7)];
            }
            *(bf8_t*)(vt + (size_t)(d0 + d_local) * SEQ + s0 + sbase) = o;
        }
        return;
    }
    // ---- q/k: rid = row (s,hh); lr = lane-in-row (8 lanes) ----
    int rid = (bid - 512) * 32 + (tid >> 3);
    int lr = tid & 7;
    int s = rid / 24, hh = rid % 24;
    const float* w;
    short* optr;
    int col0;
    if (hh < NH) {
        col0 = hh * HD + lr * 8;
        optr = q + (size_t)s * (NH * HD) + hh * HD;
        w = qw;
    } else {
        col0 = 2048 + (hh - NH) * HD + lr * 8;
        optr = k + (size_t)s * (NKV * HD) + (hh - NH) * HD;
        w = kw;
    }
    size_t poff = (size_t)s * 4096 + col0;
    bf8_t a0 = *(const bf8_t*)(pA + poff);
    bf8_t b0 = *(const bf8_t*)(pB + poff);
    bf8_t a1 = *(const bf8_t*)(pA + poff + 64);
    bf8_t b1 = *(const bf8_t*)(pB + poff + 64);
    float x0[8], x1[8];
    float ss = 0.f;
#pragma unroll
    for (int e = 0; e < 8; ++e) {
        x0[e] = bf2f(a0[e]) + bf2f(b0[e]);
        x1[e] = bf2f(a1[e]) + bf2f(b1[e]);
        ss += x0[e] * x0[e] + x1[e] * x1[e];
    }
    ss += __shfl_xor(ss, 1);
    ss += __shfl_xor(ss, 2);
    ss += __shfl_xor(ss, 4);
    float sc = rsqrtf(ss / (float)HD + EPS);
    float wlo[8], whi[8];
    *(float4*)&wlo[0] = *(const float4*)(w + lr * 8);
    *(float4*)&wlo[4] = *(const float4*)(w + lr * 8 + 4);
    *(float4*)&whi[0] = *(const float4*)(w + 64 + lr * 8);
    *(float4*)&whi[4] = *(const float4*)(w + 64 + lr * 8 + 4);
    float p = (float)pos[s];
    bf8_t o0, o1;
#pragma unroll
    for (int e = 0; e < 8; ++e) {
        float j = (float)(lr * 8 + e);
        float inv = __expf(j * -0.14391156831f);   // 10000^(-j/64)
        float fr = p * inv;
        float sn, cs;
        __sincosf(fr, &sn, &cs);
        float xn0 = x0[e] * sc * wlo[e];
        float xn1 = x1[e] * sc * whi[e];
        o0[e] = f2bf(xn0 * cs - xn1 * sn);
        o1[e] = f2bf(xn1 * cs + xn0 * sn);
    }
    *(bf8_t*)(optr + lr * 8) = o0;
    *(bf8_t*)(optr + 64 + lr * 8) = o1;
}

// ---------------- 4. MFMA flash attention v6: swapped-QK^T, lane-local rows ----
__device__ __forceinline__ void attn_stage(
    short (&kb)[64][128], short (&vb)[128][64],
    const short* __restrict__ kg, const short* __restrict__ vg,
    int t0, const int (&kinv)[4], const int (&vinv)[4], int wv) {
#pragma unroll
    for (int it = 0; it < 4; ++it) {
        gload16(kg + (size_t)t0 * (NKV * HD) + kinv[it], &kb[wv * 16 + it * 4][0]);
        gload16(vg + t0 + vinv[it], &vb[wv * 32 + it * 8][0]);
    }
}

__device__ __forceinline__ void attn_tile(
    const short (&kb)[64][128], const short (&vb)[128][64],
    short (&psh)[4][2][16][64],
    const bf8_t (&qf)[2][4], f4_t (&of)[2][8],
    float (&m_i)[2], float (&l_p)[2],
    int wv, int n, int qd, int koff) {
    f4_t sc[2][4];
#pragma unroll
    for (int g = 0; g < 2; ++g)
#pragma unroll
        for (int kk = 0; kk < 4; ++kk) sc[g][kk] = (f4_t){0.f, 0.f, 0.f, 0.f};
    __builtin_amdgcn_s_setprio(1);
#pragma unroll
    for (int kk = 0; kk < 4; ++kk) {
        int key = kk * 16 + n;
#pragma unroll
        for (int ks = 0; ks < 4; ++ks) {
            bf8_t kf = *(const bf8_t*)&kb[key][(((ks * 4 + qd) + key) & 15) * 8];
            sc[0][kk] = __builtin_amdgcn_mfma_f32_16x16x32_bf16(kf, qf[0][ks], sc[0][kk], 0, 0, 0);
            sc[1][kk] = __builtin_amdgcn_mfma_f32_16x16x32_bf16(kf, qf[1][ks], sc[1][kk], 0, 0, 0);
        }
    }
    __builtin_amdgcn_s_setprio(0);
#pragma unroll
    for (int g = 0; g < 2; ++g) {
        int rows0 = wv * 32 + g * 16;
        int qrow = rows0 + n;
        if (koff + 63 > rows0) {
#pragma unroll
            for (int kk = 0; kk < 4; ++kk)
#pragma unroll
                for (int r = 0; r < 4; ++r)
                    if (koff + kk * 16 + qd * 4 + r > qrow) sc[g][kk][r] = -1e30f;
        }
        float m01 = fmaxf(fmaxf(fmaxf(sc[g][0][0], sc[g][0][1]), fmaxf(sc[g][0][2], sc[g][0][3])),
                          fmaxf(fmaxf(sc[g][1][0], sc[g][1][1]), fmaxf(sc[g][1][2], sc[g][1][3])));
        float m23 = fmaxf(fmaxf(fmaxf(sc[g][2][0], sc[g][2][1]), fmaxf(sc[g][2][2], sc[g][2][3])),
                          fmaxf(fmaxf(sc[g][3][0], sc[g][3][1]), fmaxf(sc[g][3][2], sc[g][3][3])));
        float mx = fmaxf(m01, m23);
        mx = fmaxf(mx, __shfl_xor(mx, 16));
        mx = fmaxf(mx, __shfl_xor(mx, 32));
        if (!__all(mx <= m_i[g] + DTHR)) {
            float mnew = fmaxf(m_i[g], mx);
            float al = __expf((m_i[g] - mnew) * SCALE);
            m_i[g] = mnew;
            l_p[g] *= al;
#pragma unroll
            for (int r = 0; r < 4; ++r) {
                float alr = __shfl(al, qd * 4 + r);
#pragma unroll
                for (int nb = 0; nb < 8; ++nb) of[g][nb][r] *= alr;
            }
        }
        float mcur = m_i[g];
        float lsum = 0.f;
#pragma unroll
        for (int kk = 0; kk < 4; ++kk) {
            bf4_t pk;
#pragma unroll
            for (int r = 0; r < 4; ++r) {
                float p = __expf((sc[g][kk][r] - mcur) * SCALE);
                lsum += p;
                pk[r] = f2bf(p);
            }
            *(bf4_t*)&psh[wv][g][n][(kk * 16 + qd * 4 + n * 8) & 63] = pk;
        }
        l_p[g] += lsum;
    }
    __builtin_amdgcn_wave_barrier();  // psh write->read, same wave (in-order LDS)
    __builtin_amdgcn_s_setprio(1);
#pragma unroll
    for (int ks2 = 0; ks2 < 2; ++ks2) {
        bf8_t pf0 = *(const bf8_t*)&psh[wv][0][n][((ks2 * 32 + qd * 8) + n * 8) & 63];
        bf8_t pf1 = *(const bf8_t*)&psh[wv][1][n][((ks2 * 32 + qd * 8) + n * 8) & 63];
#pragma unroll
        for (int nb = 0; nb < 8; ++nb) {
            int dim = nb * 16 + n;
            bf8_t vf = *(const bf8_t*)&vb[dim][(((ks2 * 4 + qd) + dim) & 7) * 8];
            of[0][nb] = __builtin_amdgcn_mfma_f32_16x16x32_bf16(pf0, vf, of[0][nb], 0, 0, 0);
            of[1][nb] = __builtin_amdgcn_mfma_f32_16x16x32_bf16(pf1, vf, of[1][nb], 0, 0, 0);
        }
    }
    __builtin_amdgcn_s_setprio(0);
}

__global__ __launch_bounds__(256, 2) void attn_chunk_kernel(
    const short* __restrict__ q, const short* __restrict__ k,
    const short* __restrict__ vt, short* __restrict__ opart,
    float* __restrict__ ml) {
    __shared__ short kbufA[64][128], kbufB[64][128];
    __shared__ short vbufA[128][64], vbufB[128][64];
    __shared__ short psh[4][2][16][64];   // total LDS = 80 KB -> 2 blocks/CU

    int tid = threadIdx.x;
    int wv = tid >> 6, lane = tid & 63;
    int n = lane & 15, qd = lane >> 4;

    int i = blockIdx.x;               // 512 blocks
    int hs = i >> 8, p = i & 255;
    int h = p >> 4;
    int qt = hs ? (p & 15) : (15 - (p & 15));
    int c = hs;
    int qbase = qt * 128;
    int tstart = c ? (qt + 1) : 0;
    int tcount = qt + 1;
    int kvh = h >> 1;

    int kinv[4], vinv[4];
#pragma unroll
    for (int it = 0; it < 4; ++it) {
        int key = wv * 16 + it * 4 + (lane >> 4);
        int ck = ((lane & 15) - key) & 15;
        kinv[it] = key * (NKV * HD) + kvh * HD + ck * 8;
        int dim = wv * 32 + it * 8 + (lane >> 3);
        int cv = ((lane & 7) - dim) & 7;
        vinv[it] = (kvh * HD + dim) * SEQ + cv * 8;
    }

    bf8_t qf[2][4];
#pragma unroll
    for (int g = 0; g < 2; ++g) {
        const short* qp =
            q + (size_t)(qbase + wv * 32 + g * 16 + n) * (NH * HD) + h * HD + qd * 8;
#pragma unroll
        for (int ks = 0; ks < 4; ++ks) qf[g][ks] = *(const bf8_t*)(qp + ks * 32);
    }

    f4_t of[2][8];
#pragma unroll
    for (int g = 0; g < 2; ++g)
#pragma unroll
        for (int x = 0; x < 8; ++x) of[g][x] = (f4_t){0.f, 0.f, 0.f, 0.f};
    float m_i[2] = {-1e30f, -1e30f};
    float l_p[2] = {0.f, 0.f};

    attn_stage(kbufA, vbufA, k, vt, tstart * 64, kinv, vinv, wv);
    for (int tt = 0; tt < tcount; tt += 2) {
        __syncthreads();  // drains DMA for tile tt (issued a full tile ago)
        if (tt + 1 < tcount)
            attn_stage(kbufB, vbufB, k, vt, (tstart + tt + 1) * 64, kinv, vinv, wv);
        attn_tile(kbufA, vbufA, psh, qf, of, m_i, l_p, wv, n, qd,
                  (tstart + tt) * 64 - qbase);
        if (tt + 1 < tcount) {
            __syncthreads();
            if (tt + 2 < tcount)
                attn_stage(kbufA, vbufA, k, vt, (tstart + tt + 2) * 64, kinv, vinv, wv);
            attn_tile(kbufB, vbufB, psh, qf, of, m_i, l_p, wv, n, qd,
                      (tstart + tt + 1) * 64 - qbase);
        }
    }

    float lred[2];
#pragma unroll
    for (int g = 0; g < 2; ++g) {
        float l = l_p[g];
        l += __shfl_xor(l, 16);
        l += __shfl_xor(l, 32);
        lred[g] = l;
    }

    size_t pb = ((size_t)(h * 16 + qt)) * 2 + c;
    short* op = opart + pb * (128 * 128);
#pragma unroll
    for (int g = 0; g < 2; ++g)
#pragma unroll
        for (int nb = 0; nb < 8; ++nb)
#pragma unroll
            for (int r = 0; r < 4; ++r) {
                int rl = wv * 32 + g * 16 + qd * 4 + r;
                op[rl * 128 + nb * 16 + n] = f2bf(of[g][nb][r]);
            }
    if (qd == 0) {
#pragma unroll
        for (int g = 0; g < 2; ++g) {
            int rl = wv * 32 + g * 16 + n;
            ml[pb * 256 + rl * 2] = m_i[g] * SCALE;   // pre-scaled for merge
            ml[pb * 256 + rl * 2 + 1] = lred[g];
        }
    }
}

// ---------------- 4b. merge the two k-chunk partials per q-tile ----------------
__global__ __launch_bounds__(256) void attn_merge_kernel(
    const short* __restrict__ opart, const float* __restrict__ ml,
    short* __restrict__ o) {
    int bid = blockIdx.x;             // 256: h*16 + qt
    int h = bid >> 4, qt = bid & 15;
    int tid = threadIdx.x;
    int r = tid >> 1, hf = tid & 1;   // row 0..127, dim half
    size_t pb0 = ((size_t)(h * 16 + qt)) * 2;
    size_t pb1 = pb0 + 1;
    float m0 = ml[pb0 * 256 + r * 2], l0 = ml[pb0 * 256 + r * 2 + 1];
    float m1 = ml[pb1 * 256 + r * 2], l1 = ml[pb1 * 256 + r * 2 + 1];
    float M = fmaxf(m0, m1);
    float w0 = __expf(m0 - M), w1 = __expf(m1 - M);
    float invL = 1.0f / (w0 * l0 + w1 * l1);
    int row = qt * 128 + r;
#pragma unroll
    for (int j = 0; j < 8; ++j) {
        int d0 = hf * 64 + j * 8;
        bf8_t a = *(const bf8_t*)(opart + pb0 * (128 * 128) + r * 128 + d0);
        bf8_t b = *(const bf8_t*)(opart + pb1 * (128 * 128) + r * 128 + d0);
        bf8_t e;
#pragma unroll
        for (int x = 0; x < 8; ++x)
            e[x] = f2bf((w0 * bf2f(a[x]) + w1 * bf2f(b[x])) * invL);
        *(bf8_t*)(o + (size_t)row * (NH * HD) + h * HD + d0) = e;
    }
}

// ---------------- launch ----------------
// Workspace layout (high-water 48.5 MB):
//   +0  hnb   8 MB  (prep out / gemm1 A; merge writes attn-out)
//   +8  wqb  16 MB  (gemm1 B; dead after)  -> overlaid by mid outputs:
//   +8  qbf   8 MB, +16 kbf 4 MB, +20 vtb 4 MB
//   +24 wob   8 MB  (gemm2 B)
//   +32 pB   16 MB  (gemm1 z=1 bf16 partial; dead after mid)
//   +48 mlbuf 0.5 MB
//   d_out: pA (gemm1 z=0 partial) -> opart (attn) -> final out
//   gemm2 bf16 partials: p0b=+8, p1b=+16 (qbf/kbf dead after attn)
extern "C" void kernel_launch(void* const* d_in, const int* in_sizes, int n_in,
                              void* d_out, int out_size, void* d_ws, size_t ws_size,
                              hipStream_t stream) {
    const int* positions   = (const int*)d_in[0];
    const float* hidden    = (const float*)d_in[1];
    const float* ln_w      = (const float*)d_in[2];
    const float* w_qkv     = (const float*)d_in[3];
    const float* w_o       = (const float*)d_in[4];
    const float* q_norm_w  = (const float*)d_in[5];
    const float* k_norm_w  = (const float*)d_in[6];
    float* out = (float*)d_out;

    char* base = (char*)d_ws;
    short* hnb   = (short*)(base);
    short* wqb   = (short*)(base + ((size_t)8 << 20));
    short* qbf   = (short*)(base + ((size_t)8 << 20));
    short* kbf   = (short*)(base + ((size_t)16 << 20));
    short* vtb   = (short*)(base + ((size_t)20 << 20));
    short* wob   = (short*)(base + ((size_t)24 << 20));
    short* pB    = (short*)(base + ((size_t)32 << 20));
    float* mlbuf = (float*)(base + ((size_t)48 << 20));
    short* pA    = (short*)d_out;
    short* opart = (short*)d_out;
    short* p0b   = (short*)(base + ((size_t)8 << 20));
    short* p1b   = (short*)(base + ((size_t)16 << 20));

    prep_kernel<<<8192, 256, 0, stream>>>(w_qkv, wqb, w_o, wob, hidden, ln_w, hnb);
    gemm1_v8_kernel<<<dim3(16, 8, 2), 512, 0, stream>>>(hnb, wqb, pA, pB);
    mid_kernel<<<512 + 1536, 256, 0, stream>>>(
        pA, pB, vtb, qbf, kbf, q_norm_w, k_norm_w, positions);
    attn_chunk_kernel<<<512, 256, 0, stream>>>(qbf, kbf, vtb, opart, mlbuf);
    attn_merge_kernel<<<256, 256, 0, stream>>>(opart, mlbuf, hnb);
    gemm_mfma_kernel<<<dim3(16, 16, 2), 256, 0, stream>>>(
        hnb, wob, p0b, p1b, SEQ, NH * HD, HID);
    splitk_reduce_kernel<<<2048, 256, 0, stream>>>(p0b, p1b, out);
}